// Round 7
// baseline (445.368 us; speedup 1.0000x reference)
//
#include <hip/hip_runtime.h>
#include <hip/hip_bf16.h>

#define D_   256
#define NH_  8
#define NL_  4
#define NP_  4
#define DFF_ 1024
#define BS_  8
#define NQ_  300
#define DH_  32
#define S_TOT 19947
#define EPS_ 1e-5f

typedef __bf16 bf16x8 __attribute__((ext_vector_type(8)));
typedef __bf16 bf16x4 __attribute__((ext_vector_type(4)));
typedef float  f32x4  __attribute__((ext_vector_type(4)));

// weight segment offsets in the bf16 weight workspace (elements)
#define W_INW  0
#define W_OUTW 196608
#define W_SOW  262144
#define W_AWW  327680
#define W_VW   360448
#define W_OPW  425984
#define W_L1W  491520
#define W_L2W  753664
#define W_TOT  1015808

// ---------------------------------------------------------------------------
// Weight cast (blocks 0..991) + value-weight MFMA-frag rearrange from fp32
// (blocks 992..1023). Elementwise cast commutes with the gather -> identical.
// ---------------------------------------------------------------------------
__global__ __launch_bounds__(256) void cast_w_kernel(
    const float* __restrict__ s_inw, const float* __restrict__ s_outw,
    const float* __restrict__ s_sow, const float* __restrict__ s_aww,
    const float* __restrict__ s_vw,  const float* __restrict__ s_opw,
    const float* __restrict__ s_l1w, const float* __restrict__ s_l2w,
    __bf16* __restrict__ dst, __bf16* __restrict__ Wf)
{
    if (blockIdx.x >= 992) {
        const int g = (blockIdx.x - 992) * 256 + threadIdx.x;   // 0..8191
        const int l = g & 63;
        const int t = (g >> 6) & 15;
        const int s = g >> 10;
        const int row = t * 16 + (l & 15);
        const int col = s * 32 + (l >> 4) * 8;
        const float* src = s_vw + (size_t)row * 256 + col;
        const float4 v0 = *(const float4*)src;
        const float4 v1 = *(const float4*)(src + 4);
        bf16x8 o;
        o[0] = (__bf16)v0.x; o[1] = (__bf16)v0.y;
        o[2] = (__bf16)v0.z; o[3] = (__bf16)v0.w;
        o[4] = (__bf16)v1.x; o[5] = (__bf16)v1.y;
        o[6] = (__bf16)v1.z; o[7] = (__bf16)v1.w;
        *(bf16x8*)(Wf + (size_t)g * 8) = o;
        return;
    }
    const int i = (blockIdx.x * 256 + threadIdx.x) * 4;
    if (i >= W_TOT) return;
    const float* s; int off;
    if      (i < W_OUTW) { s = s_inw;  off = W_INW;  }
    else if (i < W_SOW)  { s = s_outw; off = W_OUTW; }
    else if (i < W_AWW)  { s = s_sow;  off = W_SOW;  }
    else if (i < W_VW)   { s = s_aww;  off = W_AWW;  }
    else if (i < W_OPW)  { s = s_vw;   off = W_VW;   }
    else if (i < W_L1W)  { s = s_opw;  off = W_OPW;  }
    else if (i < W_L2W)  { s = s_l1w;  off = W_L1W;  }
    else                 { s = s_l2w;  off = W_L2W;  }
    const float4 v = *(const float4*)(s + (i - off));
    bf16x4 o;
    o[0] = (__bf16)v.x; o[1] = (__bf16)v.y;
    o[2] = (__bf16)v.z; o[3] = (__bf16)v.w;
    *(bf16x4*)(dst + i) = o;
}

// ---------------------------------------------------------------------------
// Value GEMM v8: persistent blocks, B in VGPRs, 32-ROW tiles.
// ---------------------------------------------------------------------------
__global__ __launch_bounds__(512, 4) void gemm_value(
    const float* __restrict__ A, const __bf16* __restrict__ Wf,
    const float* __restrict__ bias, __hip_bfloat16* __restrict__ C, int M)
{
    __shared__ __align__(16) __bf16 As[2][32][264];   // 33.8 KB
    const int tid = threadIdx.x;
    const int wave = tid >> 6, lane = tid & 63;
    const int frow = lane & 15;
    const int k8 = (lane >> 4) * 8;

    bf16x8 bB[2][8];
#pragma unroll
    for (int j = 0; j < 2; ++j) {
        const int t = wave * 2 + j;
#pragma unroll
        for (int s = 0; s < 8; ++s)
            bB[j][s] = *(const bf16x8*)(Wf + ((size_t)(s * 16 + t) * 64 + lane) * 8);
    }
    const float bb0 = bias[wave * 32 + frow];
    const float bb1 = bias[wave * 32 + 16 + frow];

    const int nt = (M + 31) >> 5;
    const int stride = gridDim.x;
    int tile = blockIdx.x;

    const int srow = tid >> 5;          // 0..15; thread stages rows srow, srow+16
    const int scol = (tid & 31) * 8;    // float col within row

    // ---- prologue: stage first tile (both row-halves) into buf 0 ----
    {
        int gr0 = tile * 32 + srow;      if (gr0 >= M) gr0 = M - 1;
        int gr1 = tile * 32 + srow + 16; if (gr1 >= M) gr1 = M - 1;
        const float* ap0 = A + (size_t)gr0 * 256 + scol;
        const float* ap1 = A + (size_t)gr1 * 256 + scol;
        const float4 a0 = *(const float4*)ap0, a1 = *(const float4*)(ap0 + 4);
        const float4 a2 = *(const float4*)ap1, a3 = *(const float4*)(ap1 + 4);
        bf16x8 o0, o1;
        o0[0] = (__bf16)a0.x; o0[1] = (__bf16)a0.y; o0[2] = (__bf16)a0.z; o0[3] = (__bf16)a0.w;
        o0[4] = (__bf16)a1.x; o0[5] = (__bf16)a1.y; o0[6] = (__bf16)a1.z; o0[7] = (__bf16)a1.w;
        o1[0] = (__bf16)a2.x; o1[1] = (__bf16)a2.y; o1[2] = (__bf16)a2.z; o1[3] = (__bf16)a2.w;
        o1[4] = (__bf16)a3.x; o1[5] = (__bf16)a3.y; o1[6] = (__bf16)a3.z; o1[7] = (__bf16)a3.w;
        *(bf16x8*)&As[0][srow][scol]      = o0;
        *(bf16x8*)&As[0][srow + 16][scol] = o1;
    }
    __syncthreads();

    int buf = 0;
    for (; tile < nt; tile += stride, buf ^= 1) {
        // ---- issue next-tile loads (cover HBM latency under compute) ----
        const int nxt = tile + stride;
        const bool have_nxt = nxt < nt;
        float4 p0, p1, p2, p3;
        if (have_nxt) {
            int gr0 = nxt * 32 + srow;      if (gr0 >= M) gr0 = M - 1;
            int gr1 = nxt * 32 + srow + 16; if (gr1 >= M) gr1 = M - 1;
            const float* ap0 = A + (size_t)gr0 * 256 + scol;
            const float* ap1 = A + (size_t)gr1 * 256 + scol;
            p0 = *(const float4*)ap0; p1 = *(const float4*)(ap0 + 4);
            p2 = *(const float4*)ap1; p3 = *(const float4*)(ap1 + 4);
        }

        // ---- compute current tile: 2 row-frags x 2 col-tiles ----
        f32x4 acc00 = (f32x4){0.f, 0.f, 0.f, 0.f};
        f32x4 acc01 = acc00, acc10 = acc00, acc11 = acc00;
#pragma unroll
        for (int s = 0; s < 8; ++s) {
            const bf16x8 aF0 = *(const bf16x8*)&As[buf][frow][s * 32 + k8];
            const bf16x8 aF1 = *(const bf16x8*)&As[buf][16 + frow][s * 32 + k8];
            acc00 = __builtin_amdgcn_mfma_f32_16x16x32_bf16(aF0, bB[0][s], acc00, 0, 0, 0);
            acc01 = __builtin_amdgcn_mfma_f32_16x16x32_bf16(aF0, bB[1][s], acc01, 0, 0, 0);
            acc10 = __builtin_amdgcn_mfma_f32_16x16x32_bf16(aF1, bB[0][s], acc10, 0, 0, 0);
            acc11 = __builtin_amdgcn_mfma_f32_16x16x32_bf16(aF1, bB[1][s], acc11, 0, 0, 0);
        }

        // ---- C store ----
        const int m0 = tile * 32;
        const int row0 = (lane >> 4) * 4;
        const int col0 = wave * 32 + frow;
#pragma unroll
        for (int r = 0; r < 4; ++r) {
            const int gr = m0 + row0 + r;
            if (gr < M) {
                __hip_bfloat16* cp = C + (size_t)gr * 256 + col0;
                cp[0]  = __float2bfloat16(acc00[r] + bb0);
                cp[16] = __float2bfloat16(acc01[r] + bb1);
            }
            const int gr1 = gr + 16;
            if (gr1 < M) {
                __hip_bfloat16* cp = C + (size_t)gr1 * 256 + col0;
                cp[0]  = __float2bfloat16(acc10[r] + bb0);
                cp[16] = __float2bfloat16(acc11[r] + bb1);
            }
        }

        // ---- publish prefetched tile into the other buffer ----
        if (have_nxt) {
            bf16x8 o0, o1;
            o0[0] = (__bf16)p0.x; o0[1] = (__bf16)p0.y; o0[2] = (__bf16)p0.z; o0[3] = (__bf16)p0.w;
            o0[4] = (__bf16)p1.x; o0[5] = (__bf16)p1.y; o0[6] = (__bf16)p1.z; o0[7] = (__bf16)p1.w;
            o1[0] = (__bf16)p2.x; o1[1] = (__bf16)p2.y; o1[2] = (__bf16)p2.z; o1[3] = (__bf16)p2.w;
            o1[4] = (__bf16)p3.x; o1[5] = (__bf16)p3.y; o1[6] = (__bf16)p3.z; o1[7] = (__bf16)p3.w;
            *(bf16x8*)&As[buf ^ 1][srow][scol]      = o0;
            *(bf16x8*)&As[buf ^ 1][srow + 16][scol] = o1;
        }
        __syncthreads();
    }
}

// ---------------------------------------------------------------------------
// Small-M GEMM: C[M,N](f32) = (A (+A2 for cols<N1))[M,K](fp32) @ W^T + bias.
// Split output: cols < N1 -> C (stride N1, bias), cols >= N1 -> C2.
// ---------------------------------------------------------------------------
__global__ __launch_bounds__(256) void gemm_small(
    const float* __restrict__ A, const float* __restrict__ A2,
    const __bf16* __restrict__ W, const float* __restrict__ bias,
    float* __restrict__ C, int M, int N, int K, int relu,
    const float* __restrict__ bias2, float* __restrict__ C2, int N1)
{
    __shared__ __align__(16) __bf16 As[64][40];
    __shared__ __align__(16) __bf16 Bs[64][40];
    const int tid = threadIdx.x;
    const int wave = tid >> 6, lane = tid & 63;
    const int m0 = blockIdx.x * 64, n0 = blockIdx.y * 64;
    const int frow = lane & 15, fk = (lane >> 4) * 8;

    f32x4 acc[4];
#pragma unroll
    for (int j = 0; j < 4; ++j) acc[j] = (f32x4){0.f, 0.f, 0.f, 0.f};

    const int ar = tid >> 2;
    const int ak = (tid & 3) * 8;
    const bool a_ok = (m0 + ar) < M;
    const bool use_a2 = (A2 != nullptr) && (n0 < N1);

    for (int k0 = 0; k0 < K; k0 += 32) {
        float4 a0 = make_float4(0,0,0,0), a1 = a0;
        if (a_ok) {
            const float* ap = A + (size_t)(m0 + ar) * K + k0 + ak;
            a0 = *(const float4*)ap;
            a1 = *(const float4*)(ap + 4);
            if (use_a2) {
                const float* ap2 = A2 + (size_t)(m0 + ar) * K + k0 + ak;
                const float4 c0 = *(const float4*)ap2;
                const float4 c1 = *(const float4*)(ap2 + 4);
                a0.x += c0.x; a0.y += c0.y; a0.z += c0.z; a0.w += c0.w;
                a1.x += c1.x; a1.y += c1.y; a1.z += c1.z; a1.w += c1.w;
            }
        }
        const bf16x8 b8 = *(const bf16x8*)(W + (size_t)(n0 + ar) * K + k0 + ak);

        __syncthreads();
        bf16x8 w0;
        w0[0] = (__bf16)a0.x; w0[1] = (__bf16)a0.y; w0[2] = (__bf16)a0.z; w0[3] = (__bf16)a0.w;
        w0[4] = (__bf16)a1.x; w0[5] = (__bf16)a1.y; w0[6] = (__bf16)a1.z; w0[7] = (__bf16)a1.w;
        *(bf16x8*)&As[ar][ak] = w0;
        *(bf16x8*)&Bs[ar][ak] = b8;
        __syncthreads();

        const bf16x8 aF = *(const bf16x8*)&As[wave * 16 + frow][fk];
#pragma unroll
        for (int j = 0; j < 4; ++j) {
            const bf16x8 bF = *(const bf16x8*)&Bs[j * 16 + frow][fk];
            acc[j] = __builtin_amdgcn_mfma_f32_16x16x32_bf16(aF, bF, acc[j], 0, 0, 0);
        }
    }

    const int row = m0 + wave * 16 + (lane >> 4) * 4;
#pragma unroll
    for (int j = 0; j < 4; ++j) {
        const int col = n0 + j * 16 + frow;
        float* dst; const float* bsrc; int strideC, ccol;
        if (!C2 || col < N1) { dst = C;  bsrc = bias;  strideC = N1;     ccol = col; }
        else                 { dst = C2; bsrc = bias2; strideC = N - N1; ccol = col - N1; }
        const float bb = bsrc[ccol];
#pragma unroll
        for (int r = 0; r < 4; ++r) {
            if (row + r >= M) continue;
            float val = acc[j][r] + bb;
            if (relu) val = fmaxf(val, 0.f);
            dst[(size_t)(row + r) * strideC + ccol] = val;
        }
    }
}

// ---------------------------------------------------------------------------
// Fused self-attention: logits + in-register softmax + PV in one kernel.
// ---------------------------------------------------------------------------
__global__ __launch_bounds__(256) void attn_fused_kernel(
    const float* __restrict__ qk, const float* __restrict__ v,
    float* __restrict__ attn)
{
    __shared__ __align__(16) __bf16 Vt[32][328];
    __shared__ __align__(16) __bf16 Ps[64][328];
    const int qt = blockIdx.x, bh = blockIdx.y;
    const int b = bh >> 3, h = bh & 7;
    const int tid = threadIdx.x;
    const int wave = tid >> 6, lane = tid & 63;
    const float scale = 0.17677669529663687f;   // 1/sqrt(32)

    {
        const int d = tid & 31;
        for (int kk = tid >> 5; kk < NQ_; kk += 8)
            Vt[d][kk] = (__bf16)v[(size_t)(b * NQ_ + kk) * 256 + h * 32 + d];
        for (int i = tid; i < 32 * 20; i += 256)
            Vt[i & 31][300 + (i >> 5)] = (__bf16)0.f;
        for (int i = tid; i < 64 * 16; i += 256)
            Ps[i & 63][304 + (i >> 6)] = (__bf16)0.f;
    }

    const int m = qt * 64 + wave * 16 + (lane & 15);
    const int k8 = (lane >> 4) * 8;

    bf16x8 aF = {};
    if (m < NQ_) {
        const float* qp = qk + (size_t)(b * NQ_ + m) * 512 + h * 32 + k8;
        const float4 q0 = *(const float4*)qp;
        const float4 q1 = *(const float4*)(qp + 4);
        aF[0] = (__bf16)q0.x; aF[1] = (__bf16)q0.y;
        aF[2] = (__bf16)q0.z; aF[3] = (__bf16)q0.w;
        aF[4] = (__bf16)q1.x; aF[5] = (__bf16)q1.y;
        aF[6] = (__bf16)q1.z; aF[7] = (__bf16)q1.w;
    }

    f32x4 c[19];
#pragma unroll
    for (int t = 0; t < 19; ++t) {
        const int n = t * 16 + (lane & 15);
        bf16x8 bF = {};
        if (n < NQ_) {
            const float* kp = qk + (size_t)(b * NQ_ + n) * 512 + 256 + h * 32 + k8;
            const float4 k0 = *(const float4*)kp;
            const float4 k1 = *(const float4*)(kp + 4);
            bF[0] = (__bf16)k0.x; bF[1] = (__bf16)k0.y;
            bF[2] = (__bf16)k0.z; bF[3] = (__bf16)k0.w;
            bF[4] = (__bf16)k1.x; bF[5] = (__bf16)k1.y;
            bF[6] = (__bf16)k1.z; bF[7] = (__bf16)k1.w;
        }
        f32x4 z = (f32x4){0.f, 0.f, 0.f, 0.f};
        c[t] = __builtin_amdgcn_mfma_f32_16x16x32_bf16(aF, bF, z, 0, 0, 0);
    }

    const int myc = lane & 15;
#pragma unroll
    for (int t = 0; t < 19; ++t) {
        const bool ok = (t * 16 + myc) < NQ_;
#pragma unroll
        for (int r = 0; r < 4; ++r)
            c[t][r] = ok ? c[t][r] * scale : -1e30f;
    }

    float mx[4] = {-1e30f, -1e30f, -1e30f, -1e30f};
#pragma unroll
    for (int t = 0; t < 19; ++t)
#pragma unroll
        for (int r = 0; r < 4; ++r) mx[r] = fmaxf(mx[r], c[t][r]);
#pragma unroll
    for (int off = 8; off; off >>= 1)
#pragma unroll
        for (int r = 0; r < 4; ++r)
            mx[r] = fmaxf(mx[r], __shfl_xor(mx[r], off, 64));

    float sum[4] = {0.f, 0.f, 0.f, 0.f};
#pragma unroll
    for (int t = 0; t < 19; ++t)
#pragma unroll
        for (int r = 0; r < 4; ++r) {
            const float e = __expf(c[t][r] - mx[r]);
            c[t][r] = e;
            sum[r] += e;
        }
#pragma unroll
    for (int off = 8; off; off >>= 1)
#pragma unroll
        for (int r = 0; r < 4; ++r)
            sum[r] += __shfl_xor(sum[r], off, 64);
    float inv[4];
#pragma unroll
    for (int r = 0; r < 4; ++r) inv[r] = 1.f / sum[r];

    const int lrow0 = wave * 16 + (lane >> 4) * 4;
#pragma unroll
    for (int t = 0; t < 19; ++t) {
        const int col = t * 16 + myc;
#pragma unroll
        for (int r = 0; r < 4; ++r)
            Ps[lrow0 + r][col] = (__bf16)(c[t][r] * inv[r]);
    }
    __syncthreads();

    const int lm = wave * 16 + (lane & 15);
    f32x4 acc0 = (f32x4){0.f, 0.f, 0.f, 0.f};
    f32x4 acc1 = acc0;
#pragma unroll
    for (int k0 = 0; k0 < 320; k0 += 32) {
        const bf16x8 pF = *(const bf16x8*)&Ps[lm][k0 + k8];
        const bf16x8 b0 = *(const bf16x8*)&Vt[lane & 15][k0 + k8];
        const bf16x8 b1 = *(const bf16x8*)&Vt[16 + (lane & 15)][k0 + k8];
        acc0 = __builtin_amdgcn_mfma_f32_16x16x32_bf16(pF, b0, acc0, 0, 0, 0);
        acc1 = __builtin_amdgcn_mfma_f32_16x16x32_bf16(pF, b1, acc1, 0, 0, 0);
    }

    const int row0 = qt * 64 + lrow0;
    const int col = lane & 15;
#pragma unroll
    for (int r = 0; r < 4; ++r) {
        if (row0 + r >= NQ_) continue;
        float* op = attn + (size_t)(b * NQ_ + row0 + r) * 256 + h * 32;
        op[col]      = acc0[r];
        op[col + 16] = acc1[r];
    }
}

// ---------------------------------------------------------------------------
__global__ __launch_bounds__(256) void ln_kernel(
    const float* __restrict__ x, const float* __restrict__ res,
    const float* __restrict__ g, const float* __restrict__ bt,
    float* __restrict__ out,
    const float* __restrict__ pos, float* __restrict__ out2)
{
    const int row = blockIdx.x;
    const int tid = threadIdx.x;
    const size_t idx = (size_t)row * D_ + tid;
    float v = x[idx] + (res ? res[idx] : 0.f);

    __shared__ float red[4];
    float s = v;
#pragma unroll
    for (int off = 32; off; off >>= 1) s += __shfl_xor(s, off, 64);
    if ((tid & 63) == 0) red[tid >> 6] = s;
    __syncthreads();
    const float mean = (red[0] + red[1] + red[2] + red[3]) * (1.f / D_);
    const float c = v - mean;
    __syncthreads();

    float s2 = c * c;
#pragma unroll
    for (int off = 32; off; off >>= 1) s2 += __shfl_xor(s2, off, 64);
    if ((tid & 63) == 0) red[tid >> 6] = s2;
    __syncthreads();
    const float var = (red[0] + red[1] + red[2] + red[3]) * (1.f / D_);

    const float y = c * rsqrtf(var + EPS_) * g[tid] + bt[tid];
    out[idx] = y;
    if (out2) out2[idx] = y + pos[idx];
}

// ---------------------------------------------------------------------------
// msdeform v3 (round-5 exact): 4 query-rows per block (256 thr, 2400 waves);
// 4 channels per thread via dwordx2 gathers (bit-identical bf16 unpack).
// ---------------------------------------------------------------------------
__global__ __launch_bounds__(256) void msdeform_kernel(
    const float* __restrict__ offs, const float* __restrict__ awl,
    const float* __restrict__ refp, const __hip_bfloat16* __restrict__ value,
    float* __restrict__ samp)
{
    const int rsec = threadIdx.x >> 6;             // 0..3: which row of the quad
    const int row = blockIdx.x * 4 + rsec;
    const int b = row / NQ_;                       // NQ%4==0: no batch straddle
    const int t = threadIdx.x & 63;
    const int h = t >> 3, d4 = t & 7;              // channels 4*d4 .. 4*d4+3

    __shared__ float off_s[4][256];
    __shared__ float aw_s[4][128];
    __shared__ float ref_s[4][8];
    off_s[rsec][t]       = offs[(size_t)row * 256 + t];
    off_s[rsec][t + 64]  = offs[(size_t)row * 256 + t + 64];
    off_s[rsec][t + 128] = offs[(size_t)row * 256 + t + 128];
    off_s[rsec][t + 192] = offs[(size_t)row * 256 + t + 192];
    aw_s[rsec][t]        = awl[(size_t)row * 128 + t];
    aw_s[rsec][t + 64]   = awl[(size_t)row * 128 + t + 64];
    if (t < 8) ref_s[rsec][t] = refp[(size_t)row * 8 + t];
    __syncthreads();

    float mx = -1e30f;
#pragma unroll
    for (int i = 0; i < 16; ++i) mx = fmaxf(mx, aw_s[rsec][h * 16 + i]);
    float sum = 0.f;
#pragma unroll
    for (int i = 0; i < 16; ++i) sum += __expf(aw_s[rsec][h * 16 + i] - mx);
    const float winv = 1.f / sum;

    const int Hs[4] = {100, 50, 25, 13};
    const int Wl_[4] = {150, 75, 38, 19};
    const int S0[4] = {0, 15000, 18750, 19700};

    float o0 = 0.f, o1 = 0.f, o2 = 0.f, o3 = 0.f;
    const __hip_bfloat16* vbase = value + ((size_t)b * S_TOT) * D_ + h * 32 + d4 * 4;

#pragma unroll
    for (int l = 0; l < NL_; ++l) {
        const int Hl = Hs[l], Wl = Wl_[l];
        const float rx = ref_s[rsec][l * 2], ry = ref_s[rsec][l * 2 + 1];
        const __hip_bfloat16* vl = vbase + (size_t)S0[l] * D_;
#pragma unroll
        for (int p = 0; p < NP_; ++p) {
            const int oi = ((h * NL_ + l) * NP_ + p) * 2;
            const float lx = rx + off_s[rsec][oi] / (float)Wl;
            const float ly = ry + off_s[rsec][oi + 1] / (float)Hl;
            const float x = lx * Wl - 0.5f;
            const float y = ly * Hl - 0.5f;
            const float x0f = floorf(x), y0f = floorf(y);
            const float tx = x - x0f, ty = y - y0f;
            const int x0 = (int)x0f, y0 = (int)y0f;
            const float aw = __expf(aw_s[rsec][h * 16 + l * 4 + p] - mx) * winv;

            float s0 = 0.f, s1 = 0.f, s2 = 0.f, s3 = 0.f;
#pragma unroll
            for (int cc = 0; cc < 4; ++cc) {
                const int dy = cc >> 1, dx = cc & 1;
                const int xi = x0 + dx, yi = y0 + dy;
                const float w = (dy ? ty : 1.f - ty) * (dx ? tx : 1.f - tx);
                if (xi >= 0 && xi < Wl && yi >= 0 && yi < Hl) {
                    const int idx = yi * Wl + xi;
                    const uint2 u = *(const uint2*)(vl + (size_t)idx * D_);
                    s0 += w * __uint_as_float(u.x << 16);
                    s1 += w * __uint_as_float(u.x & 0xffff0000u);
                    s2 += w * __uint_as_float(u.y << 16);
                    s3 += w * __uint_as_float(u.y & 0xffff0000u);
                }
            }
            o0 += aw * s0;
            o1 += aw * s1;
            o2 += aw * s2;
            o3 += aw * s3;
        }
    }
    float4 ov; ov.x = o0; ov.y = o1; ov.z = o2; ov.w = o3;
    *(float4*)(samp + (size_t)row * 256 + h * 32 + d4 * 4) = ov;
}

// ---------------------------------------------------------------------------
extern "C" void kernel_launch(void* const* d_in, const int* in_sizes, int n_in,
                              void* d_out, int out_size, void* d_ws, size_t ws_size,
                              hipStream_t stream)
{
    const float* tgt   = (const float*)d_in[0];
    const float* pos   = (const float*)d_in[1];
    const float* refp  = (const float*)d_in[2];
    const float* memory= (const float*)d_in[3];
    const float* in_w  = (const float*)d_in[7];
    const float* in_b  = (const float*)d_in[8];
    const float* outw  = (const float*)d_in[9];
    const float* outb  = (const float*)d_in[10];
    const float* n1g = (const float*)d_in[11]; const float* n1b = (const float*)d_in[12];
    const float* n2g = (const float*)d_in[13]; const float* n2b = (const float*)d_in[14];
    const float* n3g = (const float*)d_in[15]; const float* n3b = (const float*)d_in[16];
    const float* sow = (const float*)d_in[17]; const float* sob = (const float*)d_in[18];
    const float* aww = (const float*)d_in[19]; const float* awb = (const float*)d_in[20];
    const float* vw  = (const float*)d_in[21]; const float* vb_ = (const float*)d_in[22];
    const float* opw = (const float*)d_in[23]; const float* opb = (const float*)d_in[24];
    const float* l1w = (const float*)d_in[25]; const float* l1b = (const float*)d_in[26];
    const float* l2w = (const float*)d_in[27]; const float* l2b = (const float*)d_in[28];
    float* out = (float*)d_out;

    char* ws = (char*)d_ws;
    size_t o = 0;
    auto alloc = [&](size_t bytes) -> char* {
        char* p = ws + o;
        o += (bytes + 255) & ~(size_t)255;
        return p;
    };

    const int M = BS_ * NQ_;  // 2400
    __bf16* Wb = (__bf16*)alloc((size_t)W_TOT * 2);
    __bf16* Wf = (__bf16*)alloc((size_t)65536 * 2);
    __hip_bfloat16* value = (__hip_bfloat16*)alloc((size_t)BS_ * S_TOT * D_ * 2);
    float* qk    = (float*)alloc((size_t)M * 512 * 4);
    float* v     = (float*)alloc((size_t)M * 256 * 4);
    float* attn  = (float*)alloc((size_t)M * 256 * 4);
    float* attno = (float*)alloc((size_t)M * 256 * 4);
    float* tgt1  = (float*)alloc((size_t)M * 256 * 4);
    float* query2= (float*)alloc((size_t)M * 256 * 4);
    float* offs  = (float*)alloc((size_t)M * 256 * 4);
    float* awl   = (float*)alloc((size_t)M * 128 * 4);
    float* samp  = (float*)alloc((size_t)M * 256 * 4);
    float* t2m   = (float*)alloc((size_t)M * 256 * 4);
    float* tgt2  = (float*)alloc((size_t)M * 256 * 4);
    float* ffn1  = (float*)alloc((size_t)M * 1024 * 4);
    float* ffn2  = (float*)alloc((size_t)M * 256 * 4);

    const dim3 blk(256);
    const int MB = (M + 63) / 64;                 // 38

    // 1. weight cast + vw frag rearrange (fused)
    cast_w_kernel<<<1024, blk, 0, stream>>>(
        in_w, outw, sow, aww, vw, opw, l1w, l2w, Wb, Wf);

    // 2. fused in-projection: qk (cols 0..511, A=tgt+pos) + v (cols 512..767, A=tgt)
    gemm_small<<<dim3(MB, 12), blk, 0, stream>>>(
        tgt, pos, Wb + W_INW, in_b, qk, M, 768, 256, 0, in_b + 512, v, 512);

    // 3. self-attention (fused logits+softmax+PV)
    attn_fused_kernel<<<dim3(5, 64), blk, 0, stream>>>(qk, v, attn);

    // 4. out-projection
    gemm_small<<<dim3(MB, 4), blk, 0, stream>>>(
        attn, nullptr, Wb + W_OUTW, outb, attno, M, 256, 256, 0, nullptr, nullptr, 256);

    // 5. LN2 -> tgt1; query2 = tgt1 + pos
    ln_kernel<<<M, blk, 0, stream>>>(tgt, attno, n2g, n2b, tgt1, pos, query2);

    // 6. sampling offsets + attention weights (split-output GEMM)
    gemm_small<<<dim3(MB, 6), blk, 0, stream>>>(
        query2, nullptr, Wb + W_SOW, sob, offs, M, 384, 256, 0, awb, awl, 256);

    // 7. value projection (big GEMM, persistent, 32-row tiles)
    gemm_value<<<dim3(512), dim3(512), 0, stream>>>(memory, Wf, vb_, value, BS_ * S_TOT);

    // 8. deformable sampling
    msdeform_kernel<<<M / 4, blk, 0, stream>>>(offs, awl, refp, value, samp);

    // 9. output projection
    gemm_small<<<dim3(MB, 4), blk, 0, stream>>>(
        samp, nullptr, Wb + W_OPW, opb, t2m, M, 256, 256, 0, nullptr, nullptr, 256);

    // 10. LN1 -> tgt2
    ln_kernel<<<M, blk, 0, stream>>>(tgt1, t2m, n1g, n1b, tgt2, nullptr, nullptr);

    // 11. FFN linear1 + relu
    gemm_small<<<dim3(MB, 16), blk, 0, stream>>>(
        tgt2, nullptr, Wb + W_L1W, l1b, ffn1, M, 1024, 256, 1, nullptr, nullptr, 1024);

    // 12. FFN linear2
    gemm_small<<<dim3(MB, 4), blk, 0, stream>>>(
        ffn1, nullptr, Wb + W_L2W, l2b, ffn2, M, 256, 1024, 0, nullptr, nullptr, 256);

    // 13. LN3 -> out
    ln_kernel<<<M, blk, 0, stream>>>(tgt2, ffn2, n3g, n3b, out, nullptr, nullptr);
}

// Round 8
// 433.169 us; speedup vs baseline: 1.0282x; 1.0282x over previous
//
#include <hip/hip_runtime.h>
#include <hip/hip_bf16.h>

#define D_   256
#define NH_  8
#define NL_  4
#define NP_  4
#define DFF_ 1024
#define BS_  8
#define NQ_  300
#define DH_  32
#define S_TOT 19947
#define EPS_ 1e-5f

typedef __bf16 bf16x8 __attribute__((ext_vector_type(8)));
typedef __bf16 bf16x4 __attribute__((ext_vector_type(4)));
typedef float  f32x4  __attribute__((ext_vector_type(4)));

// weight segment offsets in the bf16 weight workspace (elements)
#define W_INW  0
#define W_OUTW 196608
#define W_SOW  262144
#define W_AWW  327680
#define W_VW   360448
#define W_OPW  425984
#define W_L1W  491520
#define W_L2W  753664
#define W_TOT  1015808

// ---------------------------------------------------------------------------
// Weight cast (blocks 0..991) + value-weight MFMA-frag rearrange from fp32
// (blocks 992..1023). Elementwise cast commutes with the gather -> identical.
// ---------------------------------------------------------------------------
__global__ __launch_bounds__(256) void cast_w_kernel(
    const float* __restrict__ s_inw, const float* __restrict__ s_outw,
    const float* __restrict__ s_sow, const float* __restrict__ s_aww,
    const float* __restrict__ s_vw,  const float* __restrict__ s_opw,
    const float* __restrict__ s_l1w, const float* __restrict__ s_l2w,
    __bf16* __restrict__ dst, __bf16* __restrict__ Wf)
{
    if (blockIdx.x >= 992) {
        const int g = (blockIdx.x - 992) * 256 + threadIdx.x;   // 0..8191
        const int l = g & 63;
        const int t = (g >> 6) & 15;
        const int s = g >> 10;
        const int row = t * 16 + (l & 15);
        const int col = s * 32 + (l >> 4) * 8;
        const float* src = s_vw + (size_t)row * 256 + col;
        const float4 v0 = *(const float4*)src;
        const float4 v1 = *(const float4*)(src + 4);
        bf16x8 o;
        o[0] = (__bf16)v0.x; o[1] = (__bf16)v0.y;
        o[2] = (__bf16)v0.z; o[3] = (__bf16)v0.w;
        o[4] = (__bf16)v1.x; o[5] = (__bf16)v1.y;
        o[6] = (__bf16)v1.z; o[7] = (__bf16)v1.w;
        *(bf16x8*)(Wf + (size_t)g * 8) = o;
        return;
    }
    const int i = (blockIdx.x * 256 + threadIdx.x) * 4;
    if (i >= W_TOT) return;
    const float* s; int off;
    if      (i < W_OUTW) { s = s_inw;  off = W_INW;  }
    else if (i < W_SOW)  { s = s_outw; off = W_OUTW; }
    else if (i < W_AWW)  { s = s_sow;  off = W_SOW;  }
    else if (i < W_VW)   { s = s_aww;  off = W_AWW;  }
    else if (i < W_OPW)  { s = s_vw;   off = W_VW;   }
    else if (i < W_L1W)  { s = s_opw;  off = W_OPW;  }
    else if (i < W_L2W)  { s = s_l1w;  off = W_L1W;  }
    else                 { s = s_l2w;  off = W_L2W;  }
    const float4 v = *(const float4*)(s + (i - off));
    bf16x4 o;
    o[0] = (__bf16)v.x; o[1] = (__bf16)v.y;
    o[2] = (__bf16)v.z; o[3] = (__bf16)v.w;
    *(bf16x4*)(dst + i) = o;
}

// ---------------------------------------------------------------------------
// Value GEMM v6 (round-5 exact, session best): persistent blocks, B in
// VGPRs, 16-row tiles, depth-1 register prefetch + double-buffered bf16 A
// tile in LDS. NOTE: v7 (depth-2) and v8 (32-row) BOTH regressed ~+7us —
// this operating point (~90-110 VGPR) is a validated local optimum; do not
// add register pressure here.
// ---------------------------------------------------------------------------
__global__ __launch_bounds__(512, 4) void gemm_value(
    const float* __restrict__ A, const __bf16* __restrict__ Wf,
    const float* __restrict__ bias, __hip_bfloat16* __restrict__ C, int M)
{
    __shared__ __align__(16) __bf16 As[2][16][264];   // 16.9 KB
    const int tid = threadIdx.x;
    const int wave = tid >> 6, lane = tid & 63;
    const int frow = lane & 15;
    const int k8 = (lane >> 4) * 8;

    bf16x8 bB[2][8];
#pragma unroll
    for (int j = 0; j < 2; ++j) {
        const int t = wave * 2 + j;
#pragma unroll
        for (int s = 0; s < 8; ++s)
            bB[j][s] = *(const bf16x8*)(Wf + ((size_t)(s * 16 + t) * 64 + lane) * 8);
    }
    float bb0 = bias[wave * 32 + frow];
    float bb1 = bias[wave * 32 + 16 + frow];

    const int nt = (M + 15) >> 4;
    const int stride = gridDim.x;
    int tile = blockIdx.x;

    const int srow = tid >> 5;          // 0..15
    const int scol = (tid & 31) * 8;    // float col within row

    {
        int gr = tile * 16 + srow; if (gr >= M) gr = M - 1;
        const float* ap = A + (size_t)gr * 256 + scol;
        const float4 a0 = *(const float4*)ap;
        const float4 a1 = *(const float4*)(ap + 4);
        bf16x8 o;
        o[0] = (__bf16)a0.x; o[1] = (__bf16)a0.y;
        o[2] = (__bf16)a0.z; o[3] = (__bf16)a0.w;
        o[4] = (__bf16)a1.x; o[5] = (__bf16)a1.y;
        o[6] = (__bf16)a1.z; o[7] = (__bf16)a1.w;
        *(bf16x8*)&As[0][srow][scol] = o;
    }
    __syncthreads();

    int buf = 0;
    for (; tile < nt; tile += stride, buf ^= 1) {
        const int nxt = tile + stride;
        const bool have_nxt = nxt < nt;
        float4 p0, p1;
        if (have_nxt) {
            int gr = nxt * 16 + srow; if (gr >= M) gr = M - 1;
            const float* ap = A + (size_t)gr * 256 + scol;
            p0 = *(const float4*)ap;
            p1 = *(const float4*)(ap + 4);
        }

        f32x4 acc0 = (f32x4){0.f, 0.f, 0.f, 0.f};
        f32x4 acc1 = acc0;
#pragma unroll
        for (int s = 0; s < 8; ++s) {
            const bf16x8 aF = *(const bf16x8*)&As[buf][frow][s * 32 + k8];
            acc0 = __builtin_amdgcn_mfma_f32_16x16x32_bf16(aF, bB[0][s], acc0, 0, 0, 0);
            acc1 = __builtin_amdgcn_mfma_f32_16x16x32_bf16(aF, bB[1][s], acc1, 0, 0, 0);
        }

        const int m0 = tile * 16;
        const int row0 = (lane >> 4) * 4;
        const int col0 = wave * 32 + frow;
#pragma unroll
        for (int r = 0; r < 4; ++r) {
            const int gr = m0 + row0 + r;
            if (gr < M) {
                __hip_bfloat16* cp = C + (size_t)gr * 256 + col0;
                cp[0]  = __float2bfloat16(acc0[r] + bb0);
                cp[16] = __float2bfloat16(acc1[r] + bb1);
            }
        }

        if (have_nxt) {
            bf16x8 o;
            o[0] = (__bf16)p0.x; o[1] = (__bf16)p0.y;
            o[2] = (__bf16)p0.z; o[3] = (__bf16)p0.w;
            o[4] = (__bf16)p1.x; o[5] = (__bf16)p1.y;
            o[6] = (__bf16)p1.z; o[7] = (__bf16)p1.w;
            *(bf16x8*)&As[buf ^ 1][srow][scol] = o;
        }
        __syncthreads();
    }
}

// ---------------------------------------------------------------------------
// Small-M GEMM: C[M,N](f32) = (A (+A2 for cols<N1))[M,K](fp32) @ W^T + bias.
// Split output: cols < N1 -> C (stride N1, bias), cols >= N1 -> C2.
// ---------------------------------------------------------------------------
__global__ __launch_bounds__(256) void gemm_small(
    const float* __restrict__ A, const float* __restrict__ A2,
    const __bf16* __restrict__ W, const float* __restrict__ bias,
    float* __restrict__ C, int M, int N, int K, int relu,
    const float* __restrict__ bias2, float* __restrict__ C2, int N1)
{
    __shared__ __align__(16) __bf16 As[64][40];
    __shared__ __align__(16) __bf16 Bs[64][40];
    const int tid = threadIdx.x;
    const int wave = tid >> 6, lane = tid & 63;
    const int m0 = blockIdx.x * 64, n0 = blockIdx.y * 64;
    const int frow = lane & 15, fk = (lane >> 4) * 8;

    f32x4 acc[4];
#pragma unroll
    for (int j = 0; j < 4; ++j) acc[j] = (f32x4){0.f, 0.f, 0.f, 0.f};

    const int ar = tid >> 2;
    const int ak = (tid & 3) * 8;
    const bool a_ok = (m0 + ar) < M;
    const bool use_a2 = (A2 != nullptr) && (n0 < N1);

    for (int k0 = 0; k0 < K; k0 += 32) {
        float4 a0 = make_float4(0,0,0,0), a1 = a0;
        if (a_ok) {
            const float* ap = A + (size_t)(m0 + ar) * K + k0 + ak;
            a0 = *(const float4*)ap;
            a1 = *(const float4*)(ap + 4);
            if (use_a2) {
                const float* ap2 = A2 + (size_t)(m0 + ar) * K + k0 + ak;
                const float4 c0 = *(const float4*)ap2;
                const float4 c1 = *(const float4*)(ap2 + 4);
                a0.x += c0.x; a0.y += c0.y; a0.z += c0.z; a0.w += c0.w;
                a1.x += c1.x; a1.y += c1.y; a1.z += c1.z; a1.w += c1.w;
            }
        }
        const bf16x8 b8 = *(const bf16x8*)(W + (size_t)(n0 + ar) * K + k0 + ak);

        __syncthreads();
        bf16x8 w0;
        w0[0] = (__bf16)a0.x; w0[1] = (__bf16)a0.y; w0[2] = (__bf16)a0.z; w0[3] = (__bf16)a0.w;
        w0[4] = (__bf16)a1.x; w0[5] = (__bf16)a1.y; w0[6] = (__bf16)a1.z; w0[7] = (__bf16)a1.w;
        *(bf16x8*)&As[ar][ak] = w0;
        *(bf16x8*)&Bs[ar][ak] = b8;
        __syncthreads();

        const bf16x8 aF = *(const bf16x8*)&As[wave * 16 + frow][fk];
#pragma unroll
        for (int j = 0; j < 4; ++j) {
            const bf16x8 bF = *(const bf16x8*)&Bs[j * 16 + frow][fk];
            acc[j] = __builtin_amdgcn_mfma_f32_16x16x32_bf16(aF, bF, acc[j], 0, 0, 0);
        }
    }

    const int row = m0 + wave * 16 + (lane >> 4) * 4;
#pragma unroll
    for (int j = 0; j < 4; ++j) {
        const int col = n0 + j * 16 + frow;
        float* dst; const float* bsrc; int strideC, ccol;
        if (!C2 || col < N1) { dst = C;  bsrc = bias;  strideC = N1;     ccol = col; }
        else                 { dst = C2; bsrc = bias2; strideC = N - N1; ccol = col - N1; }
        const float bb = bsrc[ccol];
#pragma unroll
        for (int r = 0; r < 4; ++r) {
            if (row + r >= M) continue;
            float val = acc[j][r] + bb;
            if (relu) val = fmaxf(val, 0.f);
            dst[(size_t)(row + r) * strideC + ccol] = val;
        }
    }
}

// ---------------------------------------------------------------------------
// Fused self-attention: logits + in-register softmax + PV in one kernel.
// ---------------------------------------------------------------------------
__global__ __launch_bounds__(256) void attn_fused_kernel(
    const float* __restrict__ qk, const float* __restrict__ v,
    float* __restrict__ attn)
{
    __shared__ __align__(16) __bf16 Vt[32][328];
    __shared__ __align__(16) __bf16 Ps[64][328];
    const int qt = blockIdx.x, bh = blockIdx.y;
    const int b = bh >> 3, h = bh & 7;
    const int tid = threadIdx.x;
    const int wave = tid >> 6, lane = tid & 63;
    const float scale = 0.17677669529663687f;   // 1/sqrt(32)

    {
        const int d = tid & 31;
        for (int kk = tid >> 5; kk < NQ_; kk += 8)
            Vt[d][kk] = (__bf16)v[(size_t)(b * NQ_ + kk) * 256 + h * 32 + d];
        for (int i = tid; i < 32 * 20; i += 256)
            Vt[i & 31][300 + (i >> 5)] = (__bf16)0.f;
        for (int i = tid; i < 64 * 16; i += 256)
            Ps[i & 63][304 + (i >> 6)] = (__bf16)0.f;
    }

    const int m = qt * 64 + wave * 16 + (lane & 15);
    const int k8 = (lane >> 4) * 8;

    bf16x8 aF = {};
    if (m < NQ_) {
        const float* qp = qk + (size_t)(b * NQ_ + m) * 512 + h * 32 + k8;
        const float4 q0 = *(const float4*)qp;
        const float4 q1 = *(const float4*)(qp + 4);
        aF[0] = (__bf16)q0.x; aF[1] = (__bf16)q0.y;
        aF[2] = (__bf16)q0.z; aF[3] = (__bf16)q0.w;
        aF[4] = (__bf16)q1.x; aF[5] = (__bf16)q1.y;
        aF[6] = (__bf16)q1.z; aF[7] = (__bf16)q1.w;
    }

    f32x4 c[19];
#pragma unroll
    for (int t = 0; t < 19; ++t) {
        const int n = t * 16 + (lane & 15);
        bf16x8 bF = {};
        if (n < NQ_) {
            const float* kp = qk + (size_t)(b * NQ_ + n) * 512 + 256 + h * 32 + k8;
            const float4 k0 = *(const float4*)kp;
            const float4 k1 = *(const float4*)(kp + 4);
            bF[0] = (__bf16)k0.x; bF[1] = (__bf16)k0.y;
            bF[2] = (__bf16)k0.z; bF[3] = (__bf16)k0.w;
            bF[4] = (__bf16)k1.x; bF[5] = (__bf16)k1.y;
            bF[6] = (__bf16)k1.z; bF[7] = (__bf16)k1.w;
        }
        f32x4 z = (f32x4){0.f, 0.f, 0.f, 0.f};
        c[t] = __builtin_amdgcn_mfma_f32_16x16x32_bf16(aF, bF, z, 0, 0, 0);
    }

    const int myc = lane & 15;
#pragma unroll
    for (int t = 0; t < 19; ++t) {
        const bool ok = (t * 16 + myc) < NQ_;
#pragma unroll
        for (int r = 0; r < 4; ++r)
            c[t][r] = ok ? c[t][r] * scale : -1e30f;
    }

    float mx[4] = {-1e30f, -1e30f, -1e30f, -1e30f};
#pragma unroll
    for (int t = 0; t < 19; ++t)
#pragma unroll
        for (int r = 0; r < 4; ++r) mx[r] = fmaxf(mx[r], c[t][r]);
#pragma unroll
    for (int off = 8; off; off >>= 1)
#pragma unroll
        for (int r = 0; r < 4; ++r)
            mx[r] = fmaxf(mx[r], __shfl_xor(mx[r], off, 64));

    float sum[4] = {0.f, 0.f, 0.f, 0.f};
#pragma unroll
    for (int t = 0; t < 19; ++t)
#pragma unroll
        for (int r = 0; r < 4; ++r) {
            const float e = __expf(c[t][r] - mx[r]);
            c[t][r] = e;
            sum[r] += e;
        }
#pragma unroll
    for (int off = 8; off; off >>= 1)
#pragma unroll
        for (int r = 0; r < 4; ++r)
            sum[r] += __shfl_xor(sum[r], off, 64);
    float inv[4];
#pragma unroll
    for (int r = 0; r < 4; ++r) inv[r] = 1.f / sum[r];

    const int lrow0 = wave * 16 + (lane >> 4) * 4;
#pragma unroll
    for (int t = 0; t < 19; ++t) {
        const int col = t * 16 + myc;
#pragma unroll
        for (int r = 0; r < 4; ++r)
            Ps[lrow0 + r][col] = (__bf16)(c[t][r] * inv[r]);
    }
    __syncthreads();

    const int lm = wave * 16 + (lane & 15);
    f32x4 acc0 = (f32x4){0.f, 0.f, 0.f, 0.f};
    f32x4 acc1 = acc0;
#pragma unroll
    for (int k0 = 0; k0 < 320; k0 += 32) {
        const bf16x8 pF = *(const bf16x8*)&Ps[lm][k0 + k8];
        const bf16x8 b0 = *(const bf16x8*)&Vt[lane & 15][k0 + k8];
        const bf16x8 b1 = *(const bf16x8*)&Vt[16 + (lane & 15)][k0 + k8];
        acc0 = __builtin_amdgcn_mfma_f32_16x16x32_bf16(pF, b0, acc0, 0, 0, 0);
        acc1 = __builtin_amdgcn_mfma_f32_16x16x32_bf16(pF, b1, acc1, 0, 0, 0);
    }

    const int row0 = qt * 64 + lrow0;
    const int col = lane & 15;
#pragma unroll
    for (int r = 0; r < 4; ++r) {
        if (row0 + r >= NQ_) continue;
        float* op = attn + (size_t)(b * NQ_ + row0 + r) * 256 + h * 32;
        op[col]      = acc0[r];
        op[col + 16] = acc1[r];
    }
}

// ---------------------------------------------------------------------------
__global__ __launch_bounds__(256) void ln_kernel(
    const float* __restrict__ x, const float* __restrict__ res,
    const float* __restrict__ g, const float* __restrict__ bt,
    float* __restrict__ out,
    const float* __restrict__ pos, float* __restrict__ out2)
{
    const int row = blockIdx.x;
    const int tid = threadIdx.x;
    const size_t idx = (size_t)row * D_ + tid;
    float v = x[idx] + (res ? res[idx] : 0.f);

    __shared__ float red[4];
    float s = v;
#pragma unroll
    for (int off = 32; off; off >>= 1) s += __shfl_xor(s, off, 64);
    if ((tid & 63) == 0) red[tid >> 6] = s;
    __syncthreads();
    const float mean = (red[0] + red[1] + red[2] + red[3]) * (1.f / D_);
    const float c = v - mean;
    __syncthreads();

    float s2 = c * c;
#pragma unroll
    for (int off = 32; off; off >>= 1) s2 += __shfl_xor(s2, off, 64);
    if ((tid & 63) == 0) red[tid >> 6] = s2;
    __syncthreads();
    const float var = (red[0] + red[1] + red[2] + red[3]) * (1.f / D_);

    const float y = c * rsqrtf(var + EPS_) * g[tid] + bt[tid];
    out[idx] = y;
    if (out2) out2[idx] = y + pos[idx];
}

// ---------------------------------------------------------------------------
// msdeform v3 (round-5 exact): 4 query-rows per block (256 thr, 2400 waves);
// 4 channels per thread via dwordx2 gathers (bit-identical bf16 unpack).
// NOTE: v4 (128-thr blocks, 8 ch/thread) halved wave-level TLP -> regressed;
// this latency-bound gather kernel needs the 2400-wave occupancy.
// ---------------------------------------------------------------------------
__global__ __launch_bounds__(256) void msdeform_kernel(
    const float* __restrict__ offs, const float* __restrict__ awl,
    const float* __restrict__ refp, const __hip_bfloat16* __restrict__ value,
    float* __restrict__ samp)
{
    const int rsec = threadIdx.x >> 6;             // 0..3: which row of the quad
    const int row = blockIdx.x * 4 + rsec;
    const int b = row / NQ_;                       // NQ%4==0: no batch straddle
    const int t = threadIdx.x & 63;
    const int h = t >> 3, d4 = t & 7;              // channels 4*d4 .. 4*d4+3

    __shared__ float off_s[4][256];
    __shared__ float aw_s[4][128];
    __shared__ float ref_s[4][8];
    off_s[rsec][t]       = offs[(size_t)row * 256 + t];
    off_s[rsec][t + 64]  = offs[(size_t)row * 256 + t + 64];
    off_s[rsec][t + 128] = offs[(size_t)row * 256 + t + 128];
    off_s[rsec][t + 192] = offs[(size_t)row * 256 + t + 192];
    aw_s[rsec][t]        = awl[(size_t)row * 128 + t];
    aw_s[rsec][t + 64]   = awl[(size_t)row * 128 + t + 64];
    if (t < 8) ref_s[rsec][t] = refp[(size_t)row * 8 + t];
    __syncthreads();

    float mx = -1e30f;
#pragma unroll
    for (int i = 0; i < 16; ++i) mx = fmaxf(mx, aw_s[rsec][h * 16 + i]);
    float sum = 0.f;
#pragma unroll
    for (int i = 0; i < 16; ++i) sum += __expf(aw_s[rsec][h * 16 + i] - mx);
    const float winv = 1.f / sum;

    const int Hs[4] = {100, 50, 25, 13};
    const int Wl_[4] = {150, 75, 38, 19};
    const int S0[4] = {0, 15000, 18750, 19700};

    float o0 = 0.f, o1 = 0.f, o2 = 0.f, o3 = 0.f;
    const __hip_bfloat16* vbase = value + ((size_t)b * S_TOT) * D_ + h * 32 + d4 * 4;

#pragma unroll
    for (int l = 0; l < NL_; ++l) {
        const int Hl = Hs[l], Wl = Wl_[l];
        const float rx = ref_s[rsec][l * 2], ry = ref_s[rsec][l * 2 + 1];
        const __hip_bfloat16* vl = vbase + (size_t)S0[l] * D_;
#pragma unroll
        for (int p = 0; p < NP_; ++p) {
            const int oi = ((h * NL_ + l) * NP_ + p) * 2;
            const float lx = rx + off_s[rsec][oi] / (float)Wl;
            const float ly = ry + off_s[rsec][oi + 1] / (float)Hl;
            const float x = lx * Wl - 0.5f;
            const float y = ly * Hl - 0.5f;
            const float x0f = floorf(x), y0f = floorf(y);
            const float tx = x - x0f, ty = y - y0f;
            const int x0 = (int)x0f, y0 = (int)y0f;
            const float aw = __expf(aw_s[rsec][h * 16 + l * 4 + p] - mx) * winv;

            float s0 = 0.f, s1 = 0.f, s2 = 0.f, s3 = 0.f;
#pragma unroll
            for (int cc = 0; cc < 4; ++cc) {
                const int dy = cc >> 1, dx = cc & 1;
                const int xi = x0 + dx, yi = y0 + dy;
                const float w = (dy ? ty : 1.f - ty) * (dx ? tx : 1.f - tx);
                if (xi >= 0 && xi < Wl && yi >= 0 && yi < Hl) {
                    const int idx = yi * Wl + xi;
                    const uint2 u = *(const uint2*)(vl + (size_t)idx * D_);
                    s0 += w * __uint_as_float(u.x << 16);
                    s1 += w * __uint_as_float(u.x & 0xffff0000u);
                    s2 += w * __uint_as_float(u.y << 16);
                    s3 += w * __uint_as_float(u.y & 0xffff0000u);
                }
            }
            o0 += aw * s0;
            o1 += aw * s1;
            o2 += aw * s2;
            o3 += aw * s3;
        }
    }
    float4 ov; ov.x = o0; ov.y = o1; ov.z = o2; ov.w = o3;
    *(float4*)(samp + (size_t)row * 256 + h * 32 + d4 * 4) = ov;
}

// ---------------------------------------------------------------------------
extern "C" void kernel_launch(void* const* d_in, const int* in_sizes, int n_in,
                              void* d_out, int out_size, void* d_ws, size_t ws_size,
                              hipStream_t stream)
{
    const float* tgt   = (const float*)d_in[0];
    const float* pos   = (const float*)d_in[1];
    const float* refp  = (const float*)d_in[2];
    const float* memory= (const float*)d_in[3];
    const float* in_w  = (const float*)d_in[7];
    const float* in_b  = (const float*)d_in[8];
    const float* outw  = (const float*)d_in[9];
    const float* outb  = (const float*)d_in[10];
    const float* n1g = (const float*)d_in[11]; const float* n1b = (const float*)d_in[12];
    const float* n2g = (const float*)d_in[13]; const float* n2b = (const float*)d_in[14];
    const float* n3g = (const float*)d_in[15]; const float* n3b = (const float*)d_in[16];
    const float* sow = (const float*)d_in[17]; const float* sob = (const float*)d_in[18];
    const float* aww = (const float*)d_in[19]; const float* awb = (const float*)d_in[20];
    const float* vw  = (const float*)d_in[21]; const float* vb_ = (const float*)d_in[22];
    const float* opw = (const float*)d_in[23]; const float* opb = (const float*)d_in[24];
    const float* l1w = (const float*)d_in[25]; const float* l1b = (const float*)d_in[26];
    const float* l2w = (const float*)d_in[27]; const float* l2b = (const float*)d_in[28];
    float* out = (float*)d_out;

    char* ws = (char*)d_ws;
    size_t o = 0;
    auto alloc = [&](size_t bytes) -> char* {
        char* p = ws + o;
        o += (bytes + 255) & ~(size_t)255;
        return p;
    };

    const int M = BS_ * NQ_;  // 2400
    __bf16* Wb = (__bf16*)alloc((size_t)W_TOT * 2);
    __bf16* Wf = (__bf16*)alloc((size_t)65536 * 2);
    __hip_bfloat16* value = (__hip_bfloat16*)alloc((size_t)BS_ * S_TOT * D_ * 2);
    float* qk    = (float*)alloc((size_t)M * 512 * 4);
    float* v     = (float*)alloc((size_t)M * 256 * 4);
    float* attn  = (float*)alloc((size_t)M * 256 * 4);
    float* attno = (float*)alloc((size_t)M * 256 * 4);
    float* tgt1  = (float*)alloc((size_t)M * 256 * 4);
    float* query2= (float*)alloc((size_t)M * 256 * 4);
    float* offs  = (float*)alloc((size_t)M * 256 * 4);
    float* awl   = (float*)alloc((size_t)M * 128 * 4);
    float* samp  = (float*)alloc((size_t)M * 256 * 4);
    float* t2m   = (float*)alloc((size_t)M * 256 * 4);
    float* tgt2  = (float*)alloc((size_t)M * 256 * 4);
    float* ffn1  = (float*)alloc((size_t)M * 1024 * 4);
    float* ffn2  = (float*)alloc((size_t)M * 256 * 4);

    const dim3 blk(256);
    const int MB = (M + 63) / 64;                 // 38

    // 1. weight cast + vw frag rearrange (fused)
    cast_w_kernel<<<1024, blk, 0, stream>>>(
        in_w, outw, sow, aww, vw, opw, l1w, l2w, Wb, Wf);

    // 2. fused in-projection: qk (cols 0..511, A=tgt+pos) + v (cols 512..767, A=tgt)
    gemm_small<<<dim3(MB, 12), blk, 0, stream>>>(
        tgt, pos, Wb + W_INW, in_b, qk, M, 768, 256, 0, in_b + 512, v, 512);

    // 3. self-attention (fused logits+softmax+PV)
    attn_fused_kernel<<<dim3(5, 64), blk, 0, stream>>>(qk, v, attn);

    // 4. out-projection
    gemm_small<<<dim3(MB, 4), blk, 0, stream>>>(
        attn, nullptr, Wb + W_OUTW, outb, attno, M, 256, 256, 0, nullptr, nullptr, 256);

    // 5. LN2 -> tgt1; query2 = tgt1 + pos
    ln_kernel<<<M, blk, 0, stream>>>(tgt, attno, n2g, n2b, tgt1, pos, query2);

    // 6. sampling offsets + attention weights (split-output GEMM)
    gemm_small<<<dim3(MB, 6), blk, 0, stream>>>(
        query2, nullptr, Wb + W_SOW, sob, offs, M, 384, 256, 0, awb, awl, 256);

    // 7. value projection (big GEMM, persistent, 16-row tiles)
    gemm_value<<<dim3(512), dim3(512), 0, stream>>>(memory, Wf, vb_, value, BS_ * S_TOT);

    // 8. deformable sampling
    msdeform_kernel<<<M / 4, blk, 0, stream>>>(offs, awl, refp, value, samp);

    // 9. output projection
    gemm_small<<<dim3(MB, 4), blk, 0, stream>>>(
        samp, nullptr, Wb + W_OPW, opb, t2m, M, 256, 256, 0, nullptr, nullptr, 256);

    // 10. LN1 -> tgt2
    ln_kernel<<<M, blk, 0, stream>>>(tgt1, t2m, n1g, n1b, tgt2, nullptr, nullptr);

    // 11. FFN linear1 + relu
    gemm_small<<<dim3(MB, 16), blk, 0, stream>>>(
        tgt2, nullptr, Wb + W_L1W, l1b, ffn1, M, 1024, 256, 1, nullptr, nullptr, 1024);

    // 12. FFN linear2
    gemm_small<<<dim3(MB, 4), blk, 0, stream>>>(
        ffn1, nullptr, Wb + W_L2W, l2b, ffn2, M, 256, 1024, 0, nullptr, nullptr, 256);

    // 13. LN3 -> out
    ln_kernel<<<M, blk, 0, stream>>>(tgt2, ffn2, n3g, n3b, out, nullptr, nullptr);
}